// Round 9
// baseline (255.272 us; speedup 1.0000x reference)
//
#include <hip/hip_runtime.h>
#include <math.h>

#define BB 4
#define HH 128
#define WW 128
#define HW (HH*WW)       // 16384
#define LSEQ HW          // 16384
#define NCH 1024         // chunks per batch
#define CLEN 16          // chunk length

typedef _Float16 half8 __attribute__((ext_vector_type(8)));
typedef float floatx4 __attribute__((ext_vector_type(4)));
typedef float floatx16 __attribute__((ext_vector_type(16)));

// ---------------- workspace layout (in floats) ----------------
constexpr size_t OFF_RAW_O = 0;                      // (B,10,H,W)
constexpr size_t OFF_RAW_N = (size_t)BB*10*HW;
constexpr size_t YSEQT_O = OFF_RAW_O + OFF_RAW_N;    // (B,9,L)
constexpr size_t YSEQT_N = (size_t)BB*9*LSEQ;
constexpr size_t YNEW_O = YSEQT_O + YSEQT_N;         // (B,9,H,W)
constexpr size_t YNEW_N = (size_t)BB*9*HW;
constexpr size_t GN1_O = YNEW_O + YNEW_N;            // raw sums (B,5,2) = 40
constexpr size_t GN1_N = 64;
constexpr size_t CH18 = (size_t)BB*18*LSEQ;
constexpr size_t CH16 = (size_t)BB*16*LSEQ;
constexpr size_t DT_O = GN1_O + GN1_N;               // (B,L,18)
constexpr size_t XI_O = DT_O + CH18;                 // (B,L,18)
constexpr size_t ZZ_O = XI_O + CH18;                 // (B,L,18)
constexpr size_t BS_O = ZZ_O + CH18;                 // (B,L,16)
constexpr size_t CS_O = BS_O + CH16;                 // (B,L,16)
constexpr size_t CARR = (size_t)BB*NCH*288;
constexpr size_t CP_O = CS_O + CH16;                 // (B,288,NCH)  t-major
constexpr size_t CHC_O = CP_O + CARR;
constexpr size_t HIN_O = CHC_O + CARR;
constexpr size_t YS_O = HIN_O + CARR;                // (B,L,18)
constexpr size_t YFIN_O = YS_O + CH18;               // (B,9,H,W)
constexpr size_t XTH_O = YFIN_O + YNEW_N;            // (B,H,W,64) halfs
constexpr size_t XTH_N = (size_t)BB*HW*32;
constexpr size_t XTL_O = XTH_O + XTH_N;              // (unused, kept for layout)
constexpr size_t OUTPRE_O = XTL_O + XTH_N;           // (B,64,H,W)
constexpr size_t OUTPRE_N = (size_t)BB*64*HW;
constexpr size_t WT_O = OUTPRE_O + OUTPRE_N;         // AH(36864 h) + AL(36864 h)
constexpr size_t AO_O = WT_O + 36864;                // AOH(9216 h) + AOL(9216 h)
constexpr size_t AMAT_O = AO_O + 9216;               // (18,16)
constexpr size_t GN2_O = AMAT_O + 288;               // raw sums (B,16,2) = 128
constexpr size_t WS_TOTAL = GN2_O + 128;

// ---------------- K0: MFMA weight frags + A matrix + zero stat sums ----------------
__global__ void prep_kernel(const float* __restrict__ dsc_w, const float* __restrict__ offw,
                            const float* __restrict__ A_log,
                            _Float16* __restrict__ AH, _Float16* __restrict__ AL,
                            _Float16* __restrict__ AOH, _Float16* __restrict__ AOL,
                            float* __restrict__ Amat,
                            float* __restrict__ gn1s, float* __restrict__ gn2s){
  int i = blockIdx.x*blockDim.x + threadIdx.x;
  if(blockIdx.x==0){
    if(threadIdx.x<40) gn1s[threadIdx.x]=0.f;
    if(threadIdx.x>=64 && threadIdx.x<192) gn2s[threadIdx.x-64]=0.f;
  }
  if(i < 36864){
    int jj = i&7, gg = (i>>3)&1, co = (i>>4)&63, ks = i>>10;
    int k = ks>>2, q = ks&3;
    int ci = q*16 + gg*8 + jj;
    float w = dsc_w[((size_t)(co*64 + ci))*9 + k];   // dsc_w (co,ci,9,1)
    _Float16 h = (_Float16)w;
    AH[i] = h;
    AL[i] = (_Float16)(w - (float)h);
  }
  int j = i - 36864;
  if(j >= 0 && j < 9216){
    int jj = j&7, lane = (j>>3)&63, ksl = j>>9;      // ksl 0..17
    int tap = ksl>>1, ks = ksl&1;
    int co = lane&15, kg = lane>>4;
    int ci = ks*32 + kg*8 + jj;
    int dy = tap/3, dx = tap%3;
    float w = (co<10) ? offw[((size_t)(co*64 + ci)*3 + dy)*3 + dx] : 0.f;
    _Float16 h = (_Float16)w;
    AOH[j] = h;
    AOL[j] = (_Float16)(w - (float)h);
  }
  int a = i - 46080;
  if(a >= 0 && a < 288) Amat[a] = -__expf(A_log[a]);
}

// ---------------- K1: x (B,C,H,W) -> xTh (B,H,W,C) fp16 ----------------
__global__ __launch_bounds__(256) void transpose_x_kernel(const float* __restrict__ x,
                                                          _Float16* __restrict__ xTh){
  __shared__ float tile[64][65];
  int blk = blockIdx.x;            // B*H*2
  int w0 = (blk&1)*64;
  int h  = (blk>>1)&127;
  int b  = blk>>8;
  int lane = threadIdx.x&63, q = threadIdx.x>>6;
  #pragma unroll
  for(int r=0;r<16;r++){
    int ci = r*4 + q;
    tile[ci][lane] = x[((size_t)(b*64+ci)*HH + h)*WW + w0 + lane];
  }
  __syncthreads();
  #pragma unroll
  for(int r=0;r<16;r++){
    int w = r*4 + q;
    float v = tile[lane][w];
    xTh[(((size_t)(b*HH+h))*WW + w0 + w)*64 + lane] = (_Float16)v;
  }
}

// ---------------- K2: 3x3 offset conv; LDS row-staged MFMA + fused GN1 stats --------
__global__ __launch_bounds__(256) void off_conv_kernel(
    const _Float16* __restrict__ xTh,
    const _Float16* __restrict__ AOH, const _Float16* __restrict__ AOL,
    const float* __restrict__ offb, float* __restrict__ off_raw,
    float* __restrict__ gn1sums){
  __shared__ _Float16 R[130][72];      // staged input row, R[px] = wc=px-1 (0,129 = pads)
  __shared__ float sred[6][2];
  int blk0 = blockIdx.x;               // 512 = 8 XCDs * 64
  int blk = (blk0&7)*64 + (blk0>>3);   // XCD-contiguous h ranges
  int h = blk&127, b = blk>>7;
  int tid = threadIdx.x;
  int lane = tid&63, wv = tid>>6;
  int col = lane&15, kg = lane>>4;
  int chunk = tid&7, pxg = tid>>3;     // staging roles: 8 lanes/row-chunk
  if(tid<10) ((float*)sred)[tid]=0.f;
  floatx4 acc[2];
  acc[0] = (floatx4)0.f; acc[1] = (floatx4)0.f;
  for(int dy=0; dy<3; dy++){
    int hr = h + dy - 1;
    if(hr < 0 || hr >= HH) continue;   // block-uniform
    __syncthreads();                   // protect R from previous dy readers
    const _Float16* rowp = xTh + ((size_t)(b*HH+hr))*WW*64 + chunk*8;
    for(int px = pxg; px < 130; px += 32){
      int wc = px - 1;
      half8 v = {};
      if(wc >= 0 && wc < WW) v = *(const half8*)(rowp + (size_t)wc*64);
      *(half8*)&R[px][chunk*8] = v;
    }
    __syncthreads();
    for(int dx=0; dx<3; dx++){
      int tap = dy*3 + dx;
      #pragma unroll
      for(int ks=0; ks<2; ks++){
        half8 ah = *(const half8*)(AOH + (size_t)((tap*2+ks)*64 + lane)*8);
        half8 al = *(const half8*)(AOL + (size_t)((tap*2+ks)*64 + lane)*8);
        #pragma unroll
        for(int tt=0; tt<2; tt++){
          int px = wv*32 + tt*16 + col;
          half8 bh = *(const half8*)&R[px+dx][ks*32 + kg*8];
          acc[tt] = __builtin_amdgcn_mfma_f32_16x16x32_f16(ah, bh, acc[tt], 0,0,0);
          acc[tt] = __builtin_amdgcn_mfma_f32_16x16x32_f16(al, bh, acc[tt], 0,0,0);
        }
      }
    }
  }
  float gs[2][2] = {{0.f,0.f},{0.f,0.f}};
  #pragma unroll
  for(int tt=0; tt<2; tt++){
    #pragma unroll
    for(int r=0; r<4; r++){
      int co = kg*4 + r;
      if(co < 10){
        int px = wv*32 + tt*16 + col;
        float v = acc[tt][r] + offb[co];
        off_raw[((size_t)(b*10+co)*HH + h)*WW + px] = v;
        gs[r>>1][0] += v; gs[r>>1][1] += v*v;
      }
    }
  }
  #pragma unroll
  for(int m=1;m<16;m<<=1){
    gs[0][0]+=__shfl_xor(gs[0][0],m,16); gs[0][1]+=__shfl_xor(gs[0][1],m,16);
    gs[1][0]+=__shfl_xor(gs[1][0],m,16); gs[1][1]+=__shfl_xor(gs[1][1],m,16);
  }
  if((lane&15)==0){
    int g0 = kg*2;
    if(g0<5){ atomicAdd(&sred[g0][0],gs[0][0]); atomicAdd(&sred[g0][1],gs[0][1]); }
    if(g0+1<5){ atomicAdd(&sred[g0+1][0],gs[1][0]); atomicAdd(&sred[g0+1][1],gs[1][1]); }
  }
  __syncthreads();
  if(tid<10) atomicAdd(&gn1sums[b*10+tid], ((float*)sred)[tid]);
}

// ---------------- K4: GN1 apply (inline stats) + tanh + cumsum + zigzag ----------------
__global__ __launch_bounds__(256) void gn1_apply_kernel(const float* __restrict__ off_raw,
                                                        const float* __restrict__ gn1sums,
                                                        const float* __restrict__ gno_g,
                                                        const float* __restrict__ gno_b,
                                                        float* __restrict__ yseqT,
                                                        float* __restrict__ ynew){
  int idx = blockIdx.x*blockDim.x + threadIdx.x;   // BB*HW
  int b = idx>>14; int pix = idx&16383; int h = pix>>7, w = pix&127;
  float t[9];
  #pragma unroll
  for(int c=0;c<9;c++){
    float v = off_raw[((size_t)(b*10+c))*HW + pix];
    int gi = b*10 + (c>>1)*2;
    float S = gn1sums[gi], S2 = gn1sums[gi+1];
    float mu = S*(1.f/32768.f);
    float inv = rsqrtf(S2*(1.f/32768.f) - mu*mu + 1e-5f);
    float xx = (v-mu)*inv*gno_g[c] + gno_b[c];
    xx = fminf(fmaxf(xx,-15.f),15.f);
    float e2 = __expf(2.f*xx);
    t[c] = (e2-1.f)/(e2+1.f);
  }
  int l = (((h>>1)*WW + w)<<1) | (h&1);
  #pragma unroll
  for(int c=0;c<9;c++) yseqT[((size_t)(b*9+c))*LSEQ + l] = t[c];
  float rows[9];
  rows[4]=0.f;
  rows[5]=t[5]; rows[6]=rows[5]+t[6]; rows[7]=rows[6]+t[7]; rows[8]=rows[7]+t[8];
  rows[3]=t[3]; rows[2]=rows[3]+t[2]; rows[1]=rows[2]+t[1]; rows[0]=rows[1]+t[0];
  #pragma unroll
  for(int k=0;k<9;k++) ynew[((size_t)(b*9+k))*HW + pix] = (float)h + rows[k];
}

// ---------------- K5: mamba featurize; LDS-repacked coalesced stores ----------------
__global__ __launch_bounds__(256) void mamba_feat_kernel(
    const float* __restrict__ yseqT, const float* __restrict__ in_proj_w,
    const float* __restrict__ conv_w, const float* __restrict__ conv_b,
    const float* __restrict__ x_proj_w, const float* __restrict__ dt_w,
    const float* __restrict__ dt_b,
    float* __restrict__ DT_L, float* __restrict__ XI_L, float* __restrict__ ZZ_L,
    float* __restrict__ BS_L, float* __restrict__ CS_L){
  __shared__ float s_in[36*9], s_cw[18*4], s_cb[18], s_xw[33*18], s_dw[18], s_db[18];
  __shared__ float buf[256*18];
  for(int i=threadIdx.x;i<324;i+=256) s_in[i]=in_proj_w[i];
  for(int i=threadIdx.x;i<72;i+=256)  s_cw[i]=conv_w[i];
  for(int i=threadIdx.x;i<594;i+=256) s_xw[i]=x_proj_w[i];
  if(threadIdx.x<18){ s_cb[threadIdx.x]=conv_b[threadIdx.x];
                      s_dw[threadIdx.x]=dt_w[threadIdx.x];
                      s_db[threadIdx.x]=dt_b[threadIdx.x]; }
  __syncthreads();
  int tid = threadIdx.x;
  int idx = blockIdx.x*256 + tid;
  int b = idx>>14, l = idx&16383;
  int l0 = (blockIdx.x*256)&16383;
  float ys4[4][9];
  #pragma unroll
  for(int m=0;m<9;m++){
    const float* p = yseqT + (size_t)(b*9+m)*LSEQ;
    #pragma unroll
    for(int t=0;t<4;t++){
      int lp = l-3+t;
      ys4[t][m] = (lp>=0) ? p[lp] : 0.f;
    }
  }
  float xi[18];
  #pragma unroll
  for(int d=0;d<18;d++){
    float cacc = s_cb[d];
    #pragma unroll
    for(int t=0;t<4;t++){
      float xr = 0.f;
      #pragma unroll
      for(int m=0;m<9;m++) xr += ys4[t][m]*s_in[d*9+m];
      cacc += xr * s_cw[d*4+t];
    }
    xi[d] = cacc / (1.f + __expf(-cacc));     // silu
  }
  float dblv[33];
  #pragma unroll
  for(int j=0;j<33;j++){
    float a=0.f;
    #pragma unroll
    for(int d=0;d<18;d++) a += xi[d]*s_xw[j*18+d];
    dblv[j]=a;
  }
  float zz[18], dtv[18];
  #pragma unroll
  for(int d=0;d<18;d++){
    float a=0.f;
    #pragma unroll
    for(int m=0;m<9;m++) a += ys4[3][m]*s_in[(18+d)*9+m];
    zz[d] = a;
    float pre = dblv[0]*s_dw[d] + s_db[d];
    dtv[d] = fmaxf(pre,0.f) + __logf(1.f + __expf(-fabsf(pre)));
  }
  // --- repacked stores: LDS -> contiguous float4 global writes
  auto dump18 = [&](const float* v, float* gbase){
    #pragma unroll
    for(int d=0;d<18;d++) buf[tid*18+d] = v[d];
    __syncthreads();
    float4* gp = (float4*)gbase;
    const float4* lp = (const float4*)buf;
    for(int j=tid; j<1152; j+=256) gp[j] = lp[j];
    __syncthreads();
  };
  size_t base18 = ((size_t)b*LSEQ + l0)*18;
  dump18(xi,  XI_L + base18);
  dump18(zz,  ZZ_L + base18);
  dump18(dtv, DT_L + base18);
  auto dump16 = [&](const float* v, float* gbase){
    #pragma unroll
    for(int s=0;s<16;s++) buf[tid*16+s] = v[s];
    __syncthreads();
    float4* gp = (float4*)gbase;
    const float4* lp = (const float4*)buf;
    for(int j=tid; j<1024; j+=256) gp[j] = lp[j];
    __syncthreads();
  };
  size_t base16 = ((size_t)b*LSEQ + l0)*16;
  dump16(dblv+1,  BS_L + base16);
  dump16(dblv+17, CS_L + base16);
}

// ---------------- K6: chunk scan, thread=(b,chunk,d), 16 s-states; t-major carry out --
__global__ __launch_bounds__(288) void scan_pass1(const float* __restrict__ DT_L,
                                                  const float* __restrict__ XI_L,
                                                  const float* __restrict__ BS_L,
                                                  const float* __restrict__ Amat,
                                                  float* __restrict__ CP, float* __restrict__ CH){
  __shared__ float tile[16][18][17];     // [s][d][ck]
  int blk = blockIdx.x;                  // B * NCH/16
  int b = blk>>6; int ckb = (blk&63)<<4;
  int tid = threadIdx.x;
  int d = tid%18, ck = tid/18;
  int c = ckb + ck;
  int l0 = c*CLEN;
  float A[16];
  #pragma unroll
  for(int i=0;i<4;i++){
    float4 t = *(const float4*)(Amat + d*16 + i*4);
    A[i*4]=t.x; A[i*4+1]=t.y; A[i*4+2]=t.z; A[i*4+3]=t.w;
  }
  float h[16], P[16];
  #pragma unroll
  for(int s=0;s<16;s++){ h[s]=0.f; P[s]=1.f; }
  const float* dtp = DT_L + ((size_t)b*LSEQ + l0)*18 + d;
  const float* xip = XI_L + ((size_t)b*LSEQ + l0)*18 + d;
  const float* bsp = BS_L + ((size_t)b*LSEQ + l0)*16;
  #pragma unroll 4
  for(int st=0; st<CLEN; ++st){
    float dt  = dtp[st*18];
    float dx  = dt*xip[st*18];
    float Bv[16];
    #pragma unroll
    for(int i=0;i<4;i++){
      float4 t = *(const float4*)(bsp + st*16 + i*4);
      Bv[i*4]=t.x; Bv[i*4+1]=t.y; Bv[i*4+2]=t.z; Bv[i*4+3]=t.w;
    }
    #pragma unroll
    for(int s=0;s<16;s++){
      float a = __expf(dt*A[s]);
      h[s] = a*h[s] + dx*Bv[s];
      P[s] *= a;
    }
  }
  #pragma unroll
  for(int s=0;s<16;s++) tile[s][d][ck] = P[s];
  __syncthreads();
  {
    int t = tid; int d2 = t>>4, s2 = t&15;
    float* dst = CP + ((size_t)(b*288 + t))*NCH + ckb;
    const float* src = &tile[s2][d2][0];
    #pragma unroll
    for(int i=0;i<4;i++) ((float4*)dst)[i] = *(const float4*)(src + i*4);
  }
  __syncthreads();
  #pragma unroll
  for(int s=0;s<16;s++) tile[s][d][ck] = h[s];
  __syncthreads();
  {
    int t = tid; int d2 = t>>4, s2 = t&15;
    float* dst = CH + ((size_t)(b*288 + t))*NCH + ckb;
    const float* src = &tile[s2][d2][0];
    #pragma unroll
    for(int i=0;i<4;i++) ((float4*)dst)[i] = *(const float4*)(src + i*4);
  }
}

// ---------------- K7: parallel carry scan (wave per (b,t) chain), fully coalesced ----
__global__ __launch_bounds__(256) void scan_carry_kernel(const float* __restrict__ CP,
                                                         const float* __restrict__ CH,
                                                         float* __restrict__ HIN){
  int wid = blockIdx.x*4 + (threadIdx.x>>6);   // 0..1151
  int lane = threadIdx.x&63;
  int b = wid/288, t = wid%288;
  size_t base = ((size_t)(b*288 + t))*NCH;
  int c0 = lane*16;
  float P[16], Hh[16];
  #pragma unroll
  for(int i=0;i<4;i++){
    float4 tp = *(const float4*)(CP + base + c0 + i*4);
    float4 th = *(const float4*)(CH + base + c0 + i*4);
    P[i*4]=tp.x; P[i*4+1]=tp.y; P[i*4+2]=tp.z; P[i*4+3]=tp.w;
    Hh[i*4]=th.x; Hh[i*4+1]=th.y; Hh[i*4+2]=th.z; Hh[i*4+3]=th.w;
  }
  float aP = P[0], aH = Hh[0];
  #pragma unroll
  for(int i=1;i<16;i++){ aH = P[i]*aH + Hh[i]; aP = aP*P[i]; }
  float sP = aP, sH = aH;
  #pragma unroll
  for(int off=1; off<64; off<<=1){
    float pP = __shfl_up(sP, off, 64);
    float pH = __shfl_up(sH, off, 64);
    if(lane >= off){ sH = sP*pH + sH; sP = pP*sP; }
  }
  float eH = __shfl_up(sH, 1, 64);
  if(lane==0){ eH=0.f; }
  float cHh = eH;
  float outv[16];
  #pragma unroll
  for(int i=0;i<16;i++){
    outv[i] = cHh;
    cHh = P[i]*cHh + Hh[i];
  }
  #pragma unroll
  for(int i=0;i<4;i++){
    float4 tv; tv.x=outv[i*4]; tv.y=outv[i*4+1]; tv.z=outv[i*4+2]; tv.w=outv[i*4+3];
    *(float4*)(HIN + base + c0 + i*4) = tv;
  }
}

// ---------------- K8: chunk scan with true init (LDS-staged load) + y output -------
__global__ __launch_bounds__(288) void scan_pass2(const float* __restrict__ DT_L,
                                                  const float* __restrict__ XI_L,
                                                  const float* __restrict__ BS_L,
                                                  const float* __restrict__ CS_L,
                                                  const float* __restrict__ Amat,
                                                  const float* __restrict__ HIN,
                                                  float* __restrict__ YST_L){
  __shared__ float tile[16][18][17];     // [s][d][ck]
  int blk = blockIdx.x;
  int b = blk>>6; int ckb = (blk&63)<<4;
  int tid = threadIdx.x;
  int d = tid%18, ck = tid/18;
  int c = ckb + ck;
  int l0 = c*CLEN;
  {
    int t = tid; int d2 = t>>4, s2 = t&15;
    const float* src = HIN + ((size_t)(b*288 + t))*NCH + ckb;
    float* dst = &tile[s2][d2][0];
    #pragma unroll
    for(int i=0;i<4;i++) *(float4*)(dst + i*4) = ((const float4*)src)[i];
  }
  __syncthreads();
  float A[16];
  #pragma unroll
  for(int i=0;i<4;i++){
    float4 t = *(const float4*)(Amat + d*16 + i*4);
    A[i*4]=t.x; A[i*4+1]=t.y; A[i*4+2]=t.z; A[i*4+3]=t.w;
  }
  float h[16];
  #pragma unroll
  for(int s=0;s<16;s++) h[s] = tile[s][d][ck];
  const float* dtp = DT_L + ((size_t)b*LSEQ + l0)*18 + d;
  const float* xip = XI_L + ((size_t)b*LSEQ + l0)*18 + d;
  const float* bsp = BS_L + ((size_t)b*LSEQ + l0)*16;
  const float* csp = CS_L + ((size_t)b*LSEQ + l0)*16;
  float* ysp = YST_L + ((size_t)b*LSEQ + l0)*18 + d;
  #pragma unroll 4
  for(int st=0; st<CLEN; ++st){
    float dt  = dtp[st*18];
    float dx  = dt*xip[st*18];
    float Bv[16], Cv[16];
    #pragma unroll
    for(int i=0;i<4;i++){
      float4 t = *(const float4*)(bsp + st*16 + i*4);
      Bv[i*4]=t.x; Bv[i*4+1]=t.y; Bv[i*4+2]=t.z; Bv[i*4+3]=t.w;
      float4 u = *(const float4*)(csp + st*16 + i*4);
      Cv[i*4]=u.x; Cv[i*4+1]=u.y; Cv[i*4+2]=u.z; Cv[i*4+3]=u.w;
    }
    float pc = 0.f;
    #pragma unroll
    for(int s=0;s<16;s++){
      float a = __expf(dt*A[s]);
      h[s] = a*h[s] + dx*Bv[s];
      pc += h[s]*Cv[s];
    }
    ysp[st*18] = pc;
  }
}

// ---------------- K9: mamba epilogue + y_final; LDS-repacked coalesced loads --------
__global__ __launch_bounds__(256) void mamba_out_kernel(
    const float* __restrict__ YST_L, const float* __restrict__ XI_L,
    const float* __restrict__ ZZ_L, const float* __restrict__ Dp,
    const float* __restrict__ out_w, const float* __restrict__ altho,
    const float* __restrict__ ynew, float* __restrict__ yfin){
  __shared__ float s_ow[9*18], s_dp[18];
  __shared__ float buf[256*18];
  for(int i=threadIdx.x;i<162;i+=256) s_ow[i]=out_w[i];
  if(threadIdx.x<18) s_dp[threadIdx.x]=Dp[threadIdx.x];
  int tid = threadIdx.x;
  int idx = blockIdx.x*256 + tid;
  int b = idx>>14, l = idx&16383;
  int l0 = (blockIdx.x*256)&16383;
  size_t base18 = ((size_t)b*LSEQ + l0)*18;
  auto load18 = [&](const float* gbase, float* v){
    __syncthreads();
    float4* lp = (float4*)buf;
    const float4* gp = (const float4*)gbase;
    for(int j=tid; j<1152; j+=256) lp[j] = gp[j];
    __syncthreads();
    #pragma unroll
    for(int d=0;d<18;d++) v[d] = buf[tid*18+d];
  };
  float yst[18], xi[18], zz[18];
  load18(YST_L + base18, yst);
  load18(XI_L + base18, xi);
  load18(ZZ_L + base18, zz);
  float y[18];
  #pragma unroll
  for(int d=0;d<18;d++){
    float sz = zz[d]/(1.f+__expf(-zz[d]));
    y[d] = (yst[d] + s_dp[d]*xi[d]) * sz;
  }
  float av = altho[0];
  float sp = fmaxf(av,0.f)+__logf(1.f+__expf(-fabsf(av)));
  float wgt = fmaxf(sp, 0.01f);
  int h = ((l>>8)<<1) | (l&1);
  int w = (l>>1)&127;
  int pix = h*WW + w;
  #pragma unroll
  for(int m=0;m<9;m++){
    float a=0.f;
    #pragma unroll
    for(int d=0;d<18;d++) a += y[d]*s_ow[m*18+d];
    size_t o = ((size_t)(b*9+m))*HW + pix;
    yfin[o] = wgt*a + ynew[o];
  }
}

// ---------------- K10: fused sample + 9x1 conv; coalesced gather, async pipeline ----
__global__ __launch_bounds__(256) void sample_conv_kernel(
    const _Float16* __restrict__ xTh, const float* __restrict__ yfin,
    const _Float16* __restrict__ AH, const _Float16* __restrict__ AL,
    const float* __restrict__ bias, float* __restrict__ outpre,
    float* __restrict__ gn2sums){
  __shared__ _Float16 F[3][64][72];      // triple buffer [buf][px][ci pad 72]
  __shared__ float sred2[16][2];
  int blk0 = blockIdx.x;                 // 1024 = 8 XCDs * 128
  int blk = (blk0&7)*128 + (blk0>>3);
  int wo0 = (blk&1)*64;
  int ho  = (blk>>1)&127;
  int b   = blk>>8;
  int tid = threadIdx.x;
  int lane = tid&63;
  int wv   = tid>>6;
  int l32  = lane&31, g = lane>>5;
  int co0 = (wv&1)*32, pxh = (wv>>1)*32;
  if(tid<32) ((float*)sred2)[tid]=0.f;

  // gather roles: 8 lanes per px (chunk = ci octet) -> full-line coalescing
  int pxsub = tid>>3, chunk = tid&7;     // pxsub 0..31, chunk 0..7
  float yv[2][9];
  #pragma unroll
  for(int r=0;r<2;r++){
    const float* yp = yfin + (size_t)b*9*HW + ho*WW + wo0 + r*32 + pxsub;
    #pragma unroll
    for(int k=0;k<9;k++) yv[r][k] = yp[(size_t)k*HW];
  }
  const _Float16* ahbase = AH + ((size_t)(co0 + l32)*2 + g)*8;
  const _Float16* albase = AL + ((size_t)(co0 + l32)*2 + g)*8;

  floatx16 acc;
  #pragma unroll
  for(int r=0;r<16;r++) acc[r]=0.f;

  auto issue = [&](int k, half8* s0, half8* s1){
    #pragma unroll
    for(int r=0;r<2;r++){
      int px = r*32 + pxsub;
      float py = fminf(fmaxf(yv[r][k],0.f),127.f);
      int iy0 = (int)py;
      int iy1 = min(iy0+1,127);
      int xc = min(max(wo0 + px + k - 4, 0), 127);
      const _Float16* p0 = xTh + (((size_t)(b*HH+iy0))*WW + xc)*64 + chunk*8;
      const _Float16* p1 = xTh + (((size_t)(b*HH+iy1))*WW + xc)*64 + chunk*8;
      s0[r] = *(const half8*)p0;
      s1[r] = *(const half8*)p1;
    }
  };
  auto writeF = [&](int k, int buf, const half8* s0, const half8* s1){
    #pragma unroll
    for(int r=0;r<2;r++){
      int px = r*32 + pxsub;
      float py = fminf(fmaxf(yv[r][k],0.f),127.f);
      _Float16 wy = (_Float16)(py - floorf(py));
      half8 w8 = {wy,wy,wy,wy,wy,wy,wy,wy};
      half8 res = s0[r] + (s1[r]-s0[r])*w8;
      *(half8*)&F[buf][px][chunk*8] = res;
    }
  };

  half8 sA0[2], sA1[2], sB0[2], sB1[2];
  issue(0, sA0, sA1);
  issue(1, sB0, sB1);
  writeF(0, 0, sA0, sA1);
  __syncthreads();
  #pragma unroll
  for(int k=0;k<9;k++){
    // A-frags for this k FIRST (older than next gather -> MFMA wait won't drain it)
    half8 ahk[4], alk[4];
    #pragma unroll
    for(int q=0;q<4;q++){
      ahk[q] = *(const half8*)(ahbase + (size_t)(k*4+q)*1024);
      alk[q] = *(const half8*)(albase + (size_t)(k*4+q)*1024);
    }
    if(k<7) issue(k+2, sA0, sA1);
    if(k<8) writeF(k+1, (k+1)%3, sB0, sB1);
    __syncthreads();
    #pragma unroll
    for(int q=0;q<4;q++){
      half8 bh = *(const half8*)&F[k%3][pxh + l32][q*16 + g*8];
      acc = __builtin_amdgcn_mfma_f32_32x32x16_f16(ahk[q], bh, acc, 0,0,0);
      acc = __builtin_amdgcn_mfma_f32_32x32x16_f16(alk[q], bh, acc, 0,0,0);
    }
    if(k<7){
      #pragma unroll
      for(int r=0;r<2;r++){ sB0[r]=sA0[r]; sB1[r]=sA1[r]; }
    }
  }
  // epilogue: write + per-quad stats.  group = co0/4 + 2*(r>>2) + g
  float qs[4][2] = {{0,0},{0,0},{0,0},{0,0}};
  #pragma unroll
  for(int r=0;r<16;r++){
    int row = (r&3) + 8*(r>>2) + 4*g;
    int co = co0 + row;
    float v = acc[r] + bias[co];
    outpre[((size_t)(b*64+co))*HW + ho*WW + wo0 + pxh + l32] = v;
    qs[r>>2][0] += v; qs[r>>2][1] += v*v;
  }
  #pragma unroll
  for(int qi=0;qi<4;qi++){
    int gq = (co0>>2) + 2*qi + g;
    atomicAdd(&sred2[gq][0], qs[qi][0]);
    atomicAdd(&sred2[gq][1], qs[qi][1]);
  }
  __syncthreads();
  if(tid<32) atomicAdd(&gn2sums[b*32+tid], ((float*)sred2)[tid]);
}

// ---------------- K12: final GN apply (inline stats) ----------------
__global__ __launch_bounds__(256) void gn2_apply_kernel(const float* __restrict__ src,
                                                        const float* __restrict__ gn2sums,
                                                        const float* __restrict__ gam,
                                                        const float* __restrict__ bet,
                                                        float* __restrict__ dst){
  int idx = blockIdx.x*blockDim.x + threadIdx.x;  // BB*64*HW
  int c = (idx>>14)&63;
  int b = idx>>20;
  int gi = b*32 + (c>>2)*2;
  float S = gn2sums[gi], S2 = gn2sums[gi+1];
  float mu = S*(1.f/65536.f);
  float inv = rsqrtf(S2*(1.f/65536.f) - mu*mu + 1e-5f);
  dst[idx] = (src[idx]-mu)*inv*gam[c] + bet[c];
}

extern "C" void kernel_launch(void* const* d_in, const int* in_sizes, int n_in,
                              void* d_out, int out_size, void* d_ws, size_t ws_size,
                              hipStream_t stream){
  const float* x        = (const float*)d_in[0];
  const float* offset_w = (const float*)d_in[1];
  const float* offset_b = (const float*)d_in[2];
  const float* gno_g    = (const float*)d_in[3];
  const float* gno_b    = (const float*)d_in[4];
  const float* altho    = (const float*)d_in[5];
  const float* in_proj  = (const float*)d_in[6];
  const float* conv1d_w = (const float*)d_in[7];
  const float* conv1d_b = (const float*)d_in[8];
  const float* x_proj   = (const float*)d_in[9];
  const float* dt_w     = (const float*)d_in[10];
  const float* dt_b     = (const float*)d_in[11];
  const float* A_log    = (const float*)d_in[12];
  const float* D_p      = (const float*)d_in[13];
  const float* out_proj = (const float*)d_in[14];
  const float* dsc_w    = (const float*)d_in[15];
  const float* dsc_b    = (const float*)d_in[16];
  const float* gn_g     = (const float*)d_in[17];
  const float* gn_b     = (const float*)d_in[18];
  float* out = (float*)d_out;
  float* ws  = (float*)d_ws;
  if(ws_size < WS_TOTAL*sizeof(float)) return;

  float* off_raw = ws + OFF_RAW_O;
  float* yseqT   = ws + YSEQT_O;
  float* ynew    = ws + YNEW_O;
  float* gn1s    = ws + GN1_O;
  float* DT_L    = ws + DT_O;
  float* XI_L    = ws + XI_O;
  float* ZZ_L    = ws + ZZ_O;
  float* BS_L    = ws + BS_O;
  float* CS_L    = ws + CS_O;
  float* CP      = ws + CP_O;
  float* CH      = ws + CHC_O;
  float* HIN     = ws + HIN_O;
  float* YST_L   = ws + YS_O;
  float* yfin    = ws + YFIN_O;
  _Float16* xTh  = (_Float16*)(ws + XTH_O);
  float* outpre  = ws + OUTPRE_O;
  _Float16* AH   = (_Float16*)(ws + WT_O);
  _Float16* AL   = (_Float16*)(ws + WT_O) + 36864;
  _Float16* AOH  = (_Float16*)(ws + AO_O);
  _Float16* AOL  = (_Float16*)(ws + AO_O) + 9216;
  float* Amat    = ws + AMAT_O;
  float* gn2s    = ws + GN2_O;

  prep_kernel<<<dim3(182), dim3(256), 0, stream>>>(dsc_w, offset_w, A_log, AH, AL, AOH, AOL,
                                                   Amat, gn1s, gn2s);
  transpose_x_kernel<<<dim3(1024), dim3(256), 0, stream>>>(x, xTh);
  off_conv_kernel<<<dim3(512), dim3(256), 0, stream>>>(xTh, AOH, AOL, offset_b, off_raw, gn1s);
  gn1_apply_kernel<<<dim3(256), dim3(256), 0, stream>>>(off_raw, gn1s, gno_g, gno_b, yseqT, ynew);
  mamba_feat_kernel<<<dim3(256), dim3(256), 0, stream>>>(yseqT, in_proj, conv1d_w, conv1d_b,
                                                         x_proj, dt_w, dt_b,
                                                         DT_L, XI_L, ZZ_L, BS_L, CS_L);
  scan_pass1<<<dim3(BB*NCH/16), dim3(288), 0, stream>>>(DT_L, XI_L, BS_L, Amat, CP, CH);
  scan_carry_kernel<<<dim3(288), dim3(256), 0, stream>>>(CP, CH, HIN);
  scan_pass2<<<dim3(BB*NCH/16), dim3(288), 0, stream>>>(DT_L, XI_L, BS_L, CS_L, Amat, HIN, YST_L);
  mamba_out_kernel<<<dim3(256), dim3(256), 0, stream>>>(YST_L, XI_L, ZZ_L, D_p, out_proj, altho,
                                                        ynew, yfin);
  sample_conv_kernel<<<dim3(1024), dim3(256), 0, stream>>>(xTh, yfin, AH, AL, dsc_b, outpre, gn2s);
  gn2_apply_kernel<<<dim3(16384), dim3(256), 0, stream>>>(outpre, gn2s, gn_g, gn_b, out);
}